// Round 1
// baseline (8063.129 us; speedup 1.0000x reference)
//
#include <hip/hip_runtime.h>
#include <hip/hip_bf16.h>
#include <cstdint>
#include <cstddef>

#define F_DIM 128
#define P_DIM 2048
#define RADIUS 4
#define XT_STRIDE 68   // 64 nodes + 4 pad: bank = (4k+n)%32, conflict-free b128 frag reads

// ---------------- CSR build (once per launch) ----------------

__global__ void hist_kernel(const int* __restrict__ dst, int* __restrict__ counts, int E) {
    int e = blockIdx.x * blockDim.x + threadIdx.x;
    if (e < E) atomicAdd(&counts[dst[e]], 1);
}

__global__ __launch_bounds__(1024) void scan_kernel(const int* __restrict__ counts,
                                                    int* __restrict__ offs, int N) {
    __shared__ int buf[2][1024];
    __shared__ int carry_s;
    if (threadIdx.x == 0) carry_s = 0;
    __syncthreads();
    int nChunks = (N + 1023) >> 10;
    for (int c = 0; c < nChunks; ++c) {
        int i = (c << 10) + threadIdx.x;
        int v = (i < N) ? counts[i] : 0;
        int src = 0;
        buf[0][threadIdx.x] = v;
        __syncthreads();
        for (int off = 1; off < 1024; off <<= 1) {
            int d = src ^ 1;
            int val = buf[src][threadIdx.x];
            if (threadIdx.x >= (unsigned)off) val += buf[src][threadIdx.x - off];
            buf[d][threadIdx.x] = val;
            src = d;
            __syncthreads();
        }
        int inc = buf[src][threadIdx.x];   // inclusive scan of this chunk
        if (i < N) offs[i + 1] = carry_s + inc;
        __syncthreads();
        if (threadIdx.x == 1023) carry_s += buf[src][1023];
        __syncthreads();
    }
    if (threadIdx.x == 0) offs[0] = 0;
}

__global__ void copy_kernel(const int* __restrict__ offs, int* __restrict__ cursor, int N) {
    int i = blockIdx.x * blockDim.x + threadIdx.x;
    if (i < N) cursor[i] = offs[i];
}

__global__ void scatter_kernel(const int* __restrict__ src, const int* __restrict__ dst,
                               int* __restrict__ cursor, int* __restrict__ srcs_sorted, int E) {
    int e = blockIdx.x * blockDim.x + threadIdx.x;
    if (e < E) {
        int d = dst[e];
        int pos = atomicAdd(&cursor[d], 1);
        srcs_sorted[pos] = src[e];
    }
}

// ---------------- aggregate: agg[i] = x[i] + sum_{j in N(i)} x[j] ----------------
// one wave (64 lanes) per node, float2 per lane (128 floats/row)

__global__ __launch_bounds__(256) void agg_kernel(const float* __restrict__ x,
                                                  const int* __restrict__ offs,
                                                  const int* __restrict__ srcs,
                                                  float* __restrict__ agg, int N) {
    int wid = (blockIdx.x * blockDim.x + threadIdx.x) >> 6;
    int lane = threadIdx.x & 63;
    if (wid >= N) return;
    const float2* xr = (const float2*)x;
    float2 acc = xr[(size_t)wid * 64 + lane];
    int e0 = offs[wid], e1 = offs[wid + 1];
    for (int e = e0; e < e1; ++e) {
        int j = srcs[e];
        float2 v = xr[(size_t)j * 64 + lane];
        acc.x += v.x; acc.y += v.y;
    }
    ((float2*)agg)[(size_t)wid * 64 + lane] = acc;
}

// ---------------- fused round: lin1+relu, lin2, softmax, fp accumulate ----------------
// block = 256 threads, 64 nodes. thread: ng = tid>>4 (nodes 4ng..4ng+3), pg = tid&15 (8 cols).
// Two-pass softmax over P (online max/sum in pass 1, recompute + accumulate in pass 2)
// to avoid materializing [N,2048] logits.

__global__ __launch_bounds__(256, 3) void round_kernel(
        const float* __restrict__ agg,   // [N,128] (in-place h output allowed)
        const float* __restrict__ W1, const float* __restrict__ b1,
        const float* __restrict__ W2, const float* __restrict__ b2,
        float* __restrict__ h_out,       // [N,128]
        float* __restrict__ fp,          // [2048]
        int N) {
    __shared__ float xT[F_DIM * XT_STRIDE];   // 34.8 KB: transposed tile xT[k][n]
    __shared__ float fp_s[P_DIM];             // 8 KB
    __shared__ float m_s[64];
    __shared__ float s_s[64];
    __shared__ float rs_s[64];

    const int tid = threadIdx.x;
    const int n0 = blockIdx.x * 64;
    const int ng = tid >> 4;
    const int pg = tid & 15;
    const int f0 = pg * 8;

    for (int i = tid; i < P_DIM; i += 256) fp_s[i] = 0.f;
    if (tid < 64) { m_s[tid] = -INFINITY; s_s[tid] = 0.f; }

    // load agg tile transposed (global reads coalesced along k)
    for (int i = tid; i < 64 * F_DIM; i += 256) {
        int n = i >> 7, k = i & 127;
        float v = 0.f;
        if (n0 + n < N) v = agg[(size_t)(n0 + n) * F_DIM + k];
        xT[k * XT_STRIDE + n] = v;
    }
    __syncthreads();

    // ---- lin1: h = relu(agg @ W1 + b1), W1 streamed from L2 ----
    float hacc[4][8];
    #pragma unroll
    for (int n = 0; n < 4; ++n)
        #pragma unroll
        for (int u = 0; u < 8; ++u) hacc[n][u] = 0.f;

    const float4* W1v = (const float4*)W1;
    for (int k = 0; k < F_DIM; ++k) {
        float4 hv = *(const float4*)&xT[k * XT_STRIDE + 4 * ng];
        float4 w0 = W1v[k * 32 + 2 * pg];
        float4 w1 = W1v[k * 32 + 2 * pg + 1];
        float wv[8] = {w0.x, w0.y, w0.z, w0.w, w1.x, w1.y, w1.z, w1.w};
        float hh[4] = {hv.x, hv.y, hv.z, hv.w};
        #pragma unroll
        for (int n = 0; n < 4; ++n)
            #pragma unroll
            for (int u = 0; u < 8; ++u) hacc[n][u] += hh[n] * wv[u];
    }
    float4 bb0 = ((const float4*)b1)[2 * pg];
    float4 bb1 = ((const float4*)b1)[2 * pg + 1];
    float bv[8] = {bb0.x, bb0.y, bb0.z, bb0.w, bb1.x, bb1.y, bb1.z, bb1.w};
    float hval[4][8];
    #pragma unroll
    for (int n = 0; n < 4; ++n)
        #pragma unroll
        for (int u = 0; u < 8; ++u) {
            float v = hacc[n][u] + bv[u];
            hval[n][u] = v > 0.f ? v : 0.f;
        }
    // store h to global (next round's x); safe in-place: tile fully in LDS already
    #pragma unroll
    for (int n = 0; n < 4; ++n) {
        int node = n0 + 4 * ng + n;
        if (node < N) {
            float4 st0 = {hval[n][0], hval[n][1], hval[n][2], hval[n][3]};
            float4 st1 = {hval[n][4], hval[n][5], hval[n][6], hval[n][7]};
            float4* dst = (float4*)(h_out + (size_t)node * F_DIM + f0);
            dst[0] = st0; dst[1] = st1;
        }
    }
    __syncthreads();   // everyone done reading aggT
    // write hT into the same LDS buffer (transposed)
    #pragma unroll
    for (int n = 0; n < 4; ++n)
        #pragma unroll
        for (int u = 0; u < 8; ++u)
            xT[(f0 + u) * XT_STRIDE + 4 * ng + n] = hval[n][u];
    __syncthreads();

    // ---- lin2 pass 1: per-node online max & sum-exp over all 2048 logits ----
    const float4* W2v = (const float4*)W2;
    const float4* b2v = (const float4*)b2;
    for (int c = 0; c < P_DIM / 128; ++c) {
        int pidx = c * 32 + 2 * pg;          // float4 index of first of 2
        float lg[4][8];
        #pragma unroll
        for (int n = 0; n < 4; ++n)
            #pragma unroll
            for (int u = 0; u < 8; ++u) lg[n][u] = 0.f;
        for (int k = 0; k < F_DIM; ++k) {
            float4 hv = *(const float4*)&xT[k * XT_STRIDE + 4 * ng];
            float4 w0 = W2v[(size_t)k * (P_DIM / 4) + pidx];
            float4 w1 = W2v[(size_t)k * (P_DIM / 4) + pidx + 1];
            float wv[8] = {w0.x, w0.y, w0.z, w0.w, w1.x, w1.y, w1.z, w1.w};
            float hh[4] = {hv.x, hv.y, hv.z, hv.w};
            #pragma unroll
            for (int n = 0; n < 4; ++n)
                #pragma unroll
                for (int u = 0; u < 8; ++u) lg[n][u] += hh[n] * wv[u];
        }
        float4 c0 = b2v[pidx], c1 = b2v[pidx + 1];
        float cv[8] = {c0.x, c0.y, c0.z, c0.w, c1.x, c1.y, c1.z, c1.w};
        #pragma unroll
        for (int n = 0; n < 4; ++n) {
            float mloc = lg[n][0] + cv[0];
            #pragma unroll
            for (int u = 1; u < 8; ++u) mloc = fmaxf(mloc, lg[n][u] + cv[u]);
            float sloc = 0.f;
            #pragma unroll
            for (int u = 0; u < 8; ++u) sloc += __expf(lg[n][u] + cv[u] - mloc);
            // merge across the 16 pg lanes (consecutive lanes, same wave)
            #pragma unroll
            for (int off = 8; off >= 1; off >>= 1) {
                float om = __shfl_xor(mloc, off);
                float os = __shfl_xor(sloc, off);
                float nm = fmaxf(mloc, om);
                sloc = sloc * __expf(mloc - nm) + os * __expf(om - nm);
                mloc = nm;
            }
            if (pg == 0) {
                int idx = 4 * ng + n;
                float M = m_s[idx], S = s_s[idx];
                float nm = fmaxf(M, mloc);
                s_s[idx] = S * __expf(M - nm) + sloc * __expf(mloc - nm);
                m_s[idx] = nm;
            }
        }
    }
    __syncthreads();
    if (tid < 64) rs_s[tid] = (n0 + tid < N) ? 1.f / s_s[tid] : 0.f;
    __syncthreads();

    // ---- lin2 pass 2: recompute logits, accumulate softmax probs ----
    for (int c = 0; c < P_DIM / 128; ++c) {
        int pidx = c * 32 + 2 * pg;
        int p0 = c * 128 + f0;
        float lg[4][8];
        #pragma unroll
        for (int n = 0; n < 4; ++n)
            #pragma unroll
            for (int u = 0; u < 8; ++u) lg[n][u] = 0.f;
        for (int k = 0; k < F_DIM; ++k) {
            float4 hv = *(const float4*)&xT[k * XT_STRIDE + 4 * ng];
            float4 w0 = W2v[(size_t)k * (P_DIM / 4) + pidx];
            float4 w1 = W2v[(size_t)k * (P_DIM / 4) + pidx + 1];
            float wv[8] = {w0.x, w0.y, w0.z, w0.w, w1.x, w1.y, w1.z, w1.w};
            float hh[4] = {hv.x, hv.y, hv.z, hv.w};
            #pragma unroll
            for (int n = 0; n < 4; ++n)
                #pragma unroll
                for (int u = 0; u < 8; ++u) lg[n][u] += hh[n] * wv[u];
        }
        float4 c0 = b2v[pidx], c1 = b2v[pidx + 1];
        float cv[8] = {c0.x, c0.y, c0.z, c0.w, c1.x, c1.y, c1.z, c1.w};
        #pragma unroll
        for (int u = 0; u < 8; ++u) {
            float ps = 0.f;
            #pragma unroll
            for (int n = 0; n < 4; ++n) {
                int idx = 4 * ng + n;
                ps += __expf(lg[n][u] + cv[u] - m_s[idx]) * rs_s[idx];
            }
            // combine the 4 waves' ng-groups that share this p (lanes xor 16,32)
            ps += __shfl_xor(ps, 16);
            ps += __shfl_xor(ps, 32);
            if ((tid & 48) == 0) atomicAdd(&fp_s[p0 + u], ps);
        }
    }
    __syncthreads();
    for (int i = tid; i < P_DIM; i += 256) atomicAdd(&fp[i], fp_s[i]);
}

// ---------------- launcher ----------------

extern "C" void kernel_launch(void* const* d_in, const int* in_sizes, int n_in,
                              void* d_out, int out_size, void* d_ws, size_t ws_size,
                              hipStream_t stream) {
    const float* atoms = (const float*)d_in[0];
    const float* W1    = (const float*)d_in[1];
    const float* b1    = (const float*)d_in[2];
    const float* W2    = (const float*)d_in[3];
    const float* b2    = (const float*)d_in[4];
    const int* esrc    = (const int*)d_in[5];
    const int* edst    = (const int*)d_in[6];
    float* fp          = (float*)d_out;
    const int N = in_sizes[0] / F_DIM;
    const int E = in_sizes[5];

    char* ws = (char*)d_ws;
    float* bufA = (float*)ws;  ws += (size_t)N * F_DIM * sizeof(float);
    float* bufB = (float*)ws;  ws += (size_t)N * F_DIM * sizeof(float);
    int* offs   = (int*)ws;    ws += (size_t)(N + 1) * sizeof(int);
    int* cursor = (int*)ws;    ws += (size_t)N * sizeof(int);
    int* srcs   = (int*)ws;

    hipMemsetAsync(d_out, 0, (size_t)out_size * sizeof(float), stream);
    hipMemsetAsync(cursor, 0, (size_t)N * sizeof(int), stream);

    int eb = (E + 255) / 256;
    hist_kernel<<<eb, 256, 0, stream>>>(edst, cursor, E);
    scan_kernel<<<1, 1024, 0, stream>>>(cursor, offs, N);
    copy_kernel<<<(N + 255) / 256, 256, 0, stream>>>(offs, cursor, N);
    scatter_kernel<<<eb, 256, 0, stream>>>(esrc, edst, cursor, srcs, E);

    const float* x = atoms;
    float* aggbuf = bufA;
    for (int r = 0; r < RADIUS; ++r) {
        agg_kernel<<<(N + 3) / 4, 256, 0, stream>>>(x, offs, srcs, aggbuf, N);
        round_kernel<<<(N + 63) / 64, 256, 0, stream>>>(aggbuf, W1, b1, W2, b2,
                                                        aggbuf, fp, N);
        x = aggbuf;
        aggbuf = (aggbuf == bufA) ? bufB : bufA;
    }
}

// Round 2
// 3178.484 us; speedup vs baseline: 2.5368x; 2.5368x over previous
//
#include <hip/hip_runtime.h>
#include <hip/hip_bf16.h>
#include <cstdint>
#include <cstddef>

#define F_DIM 128
#define P_DIM 2048
#define RADIUS 4
#define HT_STRIDE 136   // ushorts per row: 272 B = 16B-aligned, 2-way bank alias only (free)

typedef short s16x8 __attribute__((ext_vector_type(8)));
typedef float f32x4 __attribute__((ext_vector_type(4)));

static __device__ __forceinline__ float bf2f(ushort u) {
    union { float f; uint i; } v; v.i = ((uint)u) << 16; return v.f;
}
static __device__ __forceinline__ ushort f2bf(float f) {
    uint u = __float_as_uint(f);
    uint r = (u + 0x7fffu + ((u >> 16) & 1u)) >> 16;   // RTN-even
    return (ushort)r;
}
static __device__ __forceinline__ f32x4 mfma16(s16x8 a, s16x8 b, f32x4 c) {
    return __builtin_amdgcn_mfma_f32_16x16x32_bf16(a, b, c, 0, 0, 0);
}

// ---------------- CSR build (once per launch) ----------------

__global__ void hist_kernel(const int* __restrict__ dst, int* __restrict__ counts, int E) {
    int e = blockIdx.x * blockDim.x + threadIdx.x;
    if (e < E) atomicAdd(&counts[dst[e]], 1);
}

__global__ __launch_bounds__(1024) void scan_kernel(const int* __restrict__ counts,
                                                    int* __restrict__ offs, int N) {
    __shared__ int buf[2][1024];
    __shared__ int carry_s;
    if (threadIdx.x == 0) carry_s = 0;
    __syncthreads();
    int nChunks = (N + 1023) >> 10;
    for (int c = 0; c < nChunks; ++c) {
        int i = (c << 10) + threadIdx.x;
        int v = (i < N) ? counts[i] : 0;
        int src = 0;
        buf[0][threadIdx.x] = v;
        __syncthreads();
        for (int off = 1; off < 1024; off <<= 1) {
            int d = src ^ 1;
            int val = buf[src][threadIdx.x];
            if (threadIdx.x >= (unsigned)off) val += buf[src][threadIdx.x - off];
            buf[d][threadIdx.x] = val;
            src = d;
            __syncthreads();
        }
        int inc = buf[src][threadIdx.x];
        if (i < N) offs[i + 1] = carry_s + inc;
        __syncthreads();
        if (threadIdx.x == 1023) carry_s += buf[src][1023];
        __syncthreads();
    }
    if (threadIdx.x == 0) offs[0] = 0;
}

__global__ void copy_kernel(const int* __restrict__ offs, int* __restrict__ cursor, int N) {
    int i = blockIdx.x * blockDim.x + threadIdx.x;
    if (i < N) cursor[i] = offs[i];
}

__global__ void scatter_kernel(const int* __restrict__ src, const int* __restrict__ dst,
                               int* __restrict__ cursor, int* __restrict__ srcs_sorted, int E) {
    int e = blockIdx.x * blockDim.x + threadIdx.x;
    if (e < E) {
        int d = dst[e];
        int pos = atomicAdd(&cursor[d], 1);
        srcs_sorted[pos] = src[e];
    }
}

// ---------------- one-time converts ----------------

__global__ void cvt_bf16_kernel(const float* __restrict__ src, ushort* __restrict__ dst, int n) {
    int i = blockIdx.x * blockDim.x + threadIdx.x;
    if (i < n) dst[i] = f2bf(src[i]);
}

// split fp32 W[K=128][P] into hi+lo bf16, swizzled to MFMA B-frag order:
// dst[(((pt*4 + kt)*2 + s)*64 + lane)*8 + j] = split_s(W[kt*32 + (lane>>4)*8 + j][pt*16 + (lane&15)])
__global__ void swizzle_split_kernel(const float* __restrict__ src, ushort* __restrict__ dst,
                                     int P, int total) {
    int d = blockIdx.x * blockDim.x + threadIdx.x;
    if (d >= total) return;
    int j    = d & 7;
    int lane = (d >> 3) & 63;
    int s    = (d >> 9) & 1;
    int kt   = (d >> 10) & 3;
    int pt   = d >> 12;
    int k = kt * 32 + (lane >> 4) * 8 + j;
    int p = pt * 16 + (lane & 15);
    float w = src[k * P + p];
    ushort hi = f2bf(w);
    ushort out = hi;
    if (s) out = f2bf(w - bf2f(hi));
    dst[d] = out;
}

// ---------------- aggregate (bf16 in, fp32 accum, bf16 out) ----------------
// one wave per node, uint (2×bf16) per lane

__global__ __launch_bounds__(256) void agg_kernel(const ushort* __restrict__ x,
                                                  const int* __restrict__ offs,
                                                  const int* __restrict__ srcs,
                                                  ushort* __restrict__ agg, int N) {
    int wid = (blockIdx.x * blockDim.x + threadIdx.x) >> 6;
    int lane = threadIdx.x & 63;
    if (wid >= N) return;
    const uint* xr = (const uint*)x;
    uint v = xr[(size_t)wid * 64 + lane];
    float a0 = bf2f((ushort)(v & 0xffffu));
    float a1 = bf2f((ushort)(v >> 16));
    int e0 = offs[wid], e1 = offs[wid + 1];
    for (int e = e0; e < e1; ++e) {
        uint u = xr[(size_t)srcs[e] * 64 + lane];
        a0 += bf2f((ushort)(u & 0xffffu));
        a1 += bf2f((ushort)(u >> 16));
    }
    ((uint*)agg)[(size_t)wid * 64 + lane] = ((uint)f2bf(a1) << 16) | (uint)f2bf(a0);
}

// ---------------- fused round: MFMA lin1+relu, lin2 two-pass online softmax ----------------
// 512 threads = 8 waves; 128 nodes/block; wave w owns nodes [blk*128+w*16, +16).

__global__ __launch_bounds__(512, 2) void round_kernel(
        const ushort* __restrict__ agg,    // [N,128] bf16
        const ushort* __restrict__ w1sw,   // swizzled hi/lo bf16, 32K ushorts
        const float*  __restrict__ b1,
        const ushort* __restrict__ w2sw,   // swizzled hi/lo bf16, 512K ushorts
        const float*  __restrict__ b2,
        ushort* __restrict__ h_out,        // [N,128] bf16 (next round x)
        float* __restrict__ fp,            // [2048]
        int N) {
    __shared__ ushort hT[128 * HT_STRIDE];  // 34 KB
    __shared__ float fp_s[P_DIM];           // 8 KB

    const int tid = threadIdx.x;
    const int w = tid >> 6;
    const int lane = tid & 63;
    const int q = lane >> 4;
    const int l15 = lane & 15;
    const int n0w = blockIdx.x * 128 + w * 16;

    for (int i = tid; i < P_DIM; i += 512) fp_s[i] = 0.f;

    // ---- lin1: h = relu(agg @ W1 + b1) ----
    s16x8 a1[4];
    {
        int node = n0w + l15;
        #pragma unroll
        for (int kt = 0; kt < 4; ++kt) {
            if (node < N)
                a1[kt] = *(const s16x8*)(agg + (size_t)node * F_DIM + kt * 32 + q * 8);
            else
                a1[kt] = (s16x8){0, 0, 0, 0, 0, 0, 0, 0};
        }
    }
    for (int pt = 0; pt < 8; ++pt) {
        f32x4 c = {0.f, 0.f, 0.f, 0.f};
        #pragma unroll
        for (int kt = 0; kt < 4; ++kt) {
            s16x8 bh = *(const s16x8*)(w1sw + (size_t)((((pt * 4 + kt) * 2 + 0) * 64 + lane)) * 8);
            s16x8 bl = *(const s16x8*)(w1sw + (size_t)((((pt * 4 + kt) * 2 + 1) * 64 + lane)) * 8);
            c = mfma16(a1[kt], bh, c);
            c = mfma16(a1[kt], bl, c);
        }
        float bb = b1[pt * 16 + l15];
        #pragma unroll
        for (int r = 0; r < 4; ++r) {
            float v = c[r] + bb;
            v = v > 0.f ? v : 0.f;
            hT[(w * 16 + q * 4 + r) * HT_STRIDE + pt * 16 + l15] = f2bf(v);
        }
    }
    __syncthreads();

    // coalesced hT -> h_out (global), guarded rows
    {
        int row = tid >> 2, seg = tid & 3;
        int gnode = blockIdx.x * 128 + row;
        if (gnode < N) {
            #pragma unroll
            for (int u = 0; u < 4; ++u) {
                int col8 = (seg * 4 + u) * 8;
                s16x8 vv = *(const s16x8*)&hT[row * HT_STRIDE + col8];
                *(s16x8*)(h_out + (size_t)gnode * F_DIM + col8) = vv;
            }
        }
    }

    // ---- lin2 A-frags from LDS (2-way bank alias only) ----
    s16x8 a2[4];
    #pragma unroll
    for (int kt = 0; kt < 4; ++kt)
        a2[kt] = *(const s16x8*)&hT[(w * 16 + l15) * HT_STRIDE + kt * 32 + q * 8];

    // ---- pass 1: online max / sum-exp over 2048 logits ----
    float m[4], s[4];
    #pragma unroll
    for (int r = 0; r < 4; ++r) { m[r] = -INFINITY; s[r] = 0.f; }

    for (int pt = 0; pt < 128; ++pt) {
        f32x4 c = {0.f, 0.f, 0.f, 0.f};
        #pragma unroll
        for (int kt = 0; kt < 4; ++kt) {
            s16x8 bh = *(const s16x8*)(w2sw + (size_t)((((pt * 4 + kt) * 2 + 0) * 64 + lane)) * 8);
            s16x8 bl = *(const s16x8*)(w2sw + (size_t)((((pt * 4 + kt) * 2 + 1) * 64 + lane)) * 8);
            c = mfma16(a2[kt], bh, c);
            c = mfma16(a2[kt], bl, c);
        }
        float bb = b2[pt * 16 + l15];
        #pragma unroll
        for (int r = 0; r < 4; ++r) {
            float v = c[r] + bb;
            float nm = fmaxf(m[r], v);
            s[r] = s[r] * __expf(m[r] - nm) + __expf(v - nm);
            m[r] = nm;
        }
        if ((pt & 3) == 3) __builtin_amdgcn_s_barrier();  // keep waves converged for L1 B-reuse
    }
    // merge (m,s) across the 16 lanes of each quad (they share the same 4 nodes)
    #pragma unroll
    for (int r = 0; r < 4; ++r) {
        #pragma unroll
        for (int off = 1; off <= 8; off <<= 1) {
            float om = __shfl_xor(m[r], off);
            float os = __shfl_xor(s[r], off);
            float nm = fmaxf(m[r], om);
            s[r] = s[r] * __expf(m[r] - nm) + os * __expf(om - nm);
            m[r] = nm;
        }
    }
    float rs[4];
    #pragma unroll
    for (int r = 0; r < 4; ++r) {
        int gnode = n0w + q * 4 + r;
        rs[r] = (gnode < N) ? 1.f / s[r] : 0.f;
    }

    // ---- pass 2: recompute logits, accumulate softmax probs into fp_s ----
    for (int pt = 0; pt < 128; ++pt) {
        f32x4 c = {0.f, 0.f, 0.f, 0.f};
        #pragma unroll
        for (int kt = 0; kt < 4; ++kt) {
            s16x8 bh = *(const s16x8*)(w2sw + (size_t)((((pt * 4 + kt) * 2 + 0) * 64 + lane)) * 8);
            s16x8 bl = *(const s16x8*)(w2sw + (size_t)((((pt * 4 + kt) * 2 + 1) * 64 + lane)) * 8);
            c = mfma16(a2[kt], bh, c);
            c = mfma16(a2[kt], bl, c);
        }
        float bb = b2[pt * 16 + l15];
        float tot = 0.f;
        #pragma unroll
        for (int r = 0; r < 4; ++r)
            tot += __expf(c[r] + bb - m[r]) * rs[r];
        tot += __shfl_xor(tot, 16);
        tot += __shfl_xor(tot, 32);
        if (lane < 16) atomicAdd(&fp_s[pt * 16 + lane], tot);
        if ((pt & 3) == 3) __builtin_amdgcn_s_barrier();
    }
    __syncthreads();
    for (int i = tid; i < P_DIM; i += 512) atomicAdd(&fp[i], fp_s[i]);
}

// ---------------- launcher ----------------

extern "C" void kernel_launch(void* const* d_in, const int* in_sizes, int n_in,
                              void* d_out, int out_size, void* d_ws, size_t ws_size,
                              hipStream_t stream) {
    const float* atoms = (const float*)d_in[0];
    const float* W1    = (const float*)d_in[1];
    const float* b1    = (const float*)d_in[2];
    const float* W2    = (const float*)d_in[3];
    const float* b2    = (const float*)d_in[4];
    const int* esrc    = (const int*)d_in[5];
    const int* edst    = (const int*)d_in[6];
    float* fp          = (float*)d_out;
    const int N = in_sizes[0] / F_DIM;
    const int E = in_sizes[5];

    char* ws = (char*)d_ws;
    ushort* xA   = (ushort*)ws;  ws += (size_t)N * F_DIM * sizeof(ushort);
    ushort* xB   = (ushort*)ws;  ws += (size_t)N * F_DIM * sizeof(ushort);
    ushort* aggb = (ushort*)ws;  ws += (size_t)N * F_DIM * sizeof(ushort);
    ushort* w1sw = (ushort*)ws;  ws += (size_t)F_DIM * F_DIM * 2 * sizeof(ushort);
    ushort* w2sw = (ushort*)ws;  ws += (size_t)F_DIM * P_DIM * 2 * sizeof(ushort);
    int* offs    = (int*)ws;     ws += (((size_t)(N + 1) * sizeof(int) + 255) & ~255ull);
    int* cursor  = (int*)ws;     ws += (((size_t)N * sizeof(int) + 255) & ~255ull);
    int* srcs    = (int*)ws;

    hipMemsetAsync(d_out, 0, (size_t)out_size * sizeof(float), stream);
    hipMemsetAsync(cursor, 0, (size_t)N * sizeof(int), stream);

    // CSR build
    int eb = (E + 255) / 256;
    hist_kernel<<<eb, 256, 0, stream>>>(edst, cursor, E);
    scan_kernel<<<1, 1024, 0, stream>>>(cursor, offs, N);
    copy_kernel<<<(N + 255) / 256, 256, 0, stream>>>(offs, cursor, N);
    scatter_kernel<<<eb, 256, 0, stream>>>(esrc, edst, cursor, srcs, E);

    // one-time converts
    int nconv = N * F_DIM;
    cvt_bf16_kernel<<<(nconv + 255) / 256, 256, 0, stream>>>(atoms, xA, nconv);
    int t1 = F_DIM * F_DIM * 2;
    swizzle_split_kernel<<<(t1 + 255) / 256, 256, 0, stream>>>(W1, w1sw, F_DIM, t1);
    int t2 = F_DIM * P_DIM * 2;
    swizzle_split_kernel<<<(t2 + 255) / 256, 256, 0, stream>>>(W2, w2sw, P_DIM, t2);

    const ushort* x = xA;
    ushort* xnext = xB;
    int rblocks = (N + 127) / 128;
    for (int r = 0; r < RADIUS; ++r) {
        agg_kernel<<<(N + 3) / 4, 256, 0, stream>>>(x, offs, srcs, aggb, N);
        round_kernel<<<rblocks, 512, 0, stream>>>(aggb, w1sw, b1, w2sw, b2,
                                                  xnext, fp, N);
        x = xnext;
        xnext = (xnext == xB) ? xA : xB;
    }
}